// Round 5
// baseline (106.949 us; speedup 1.0000x reference)
//
#include <hip/hip_runtime.h>
#include <hip/hip_bf16.h>

#define G_TOTAL 8192        // B*S = 8*1024
#define K_PTS   32
#define FEAT    43
#define TOTAL   133         // 129 rbf + 1 curv + 3 lap
#define OUTD    384

typedef __bf16 bf16x8 __attribute__((ext_vector_type(8)));
typedef float  f32x4  __attribute__((ext_vector_type(4)));

// ---------------- pack W (+bias as row 133) into bf16 MFMA fragment layout --
// wf[((ks*24 + nt)*64 + lane)*8 + j] = Wpad[k = ks*32 + (lane>>4)*8 + j][col = nt*16 + (lane&15)]
__global__ void wprep_kernel(const float* __restrict__ W,
                             const float* __restrict__ bias,
                             __bf16* __restrict__ wf) {
    int idx = blockIdx.x * blockDim.x + threadIdx.x;
    if (idx >= 5*24*64*8) return;
    const int j    = idx & 7;
    const int lane = (idx >> 3) & 63;
    const int tile = idx >> 9;
    const int nt   = tile % 24;
    const int ks   = tile / 24;
    const int k    = ks*32 + ((lane >> 4) << 3) + j;
    const int col  = nt*16 + (lane & 15);
    float v = 0.0f;
    if (k < TOTAL)       v = W[k*OUTD + col];
    else if (k == TOTAL) v = bias[col];
    wf[idx] = (__bf16)v;
}

// ---------------- main: block-per-group; wave = (point-half x 192 channels);
// full 48-KB group accumulated in swizzled LDS; perfectly-linear streaming store
__global__ __launch_bounds__(256, 3)
void main_kernel(const float* __restrict__ xyz,
                 const float* __restrict__ nxyz,
                 const __bf16* __restrict__ wf,
                 float* __restrict__ out) {
    __shared__ f32x4 lbuf[K_PTS * 96];   // 32 rows x 96 f32x4 slots = 48 KB
    const int lane = threadIdx.x & 63;
    const int wave = threadIdx.x >> 6;
    const int g    = blockIdx.x;
    const int pt   = lane & 15;          // point within half (C^T column)
    const int hi   = lane >> 4;          // channel-quad selector
    const int h    = wave & 1;           // point half: 0 -> pts 0..15, 1 -> 16..31
    const int tb   = (wave >> 1) * 12;   // tile base: 12 of 24 N-tiles

    // ---- per-group stats (each wave computes redundantly; lanes 0..31 hold one neighbor)
    const float* ng = nxyz + (size_t)g * (K_PTS * 3);
    float nx = 0.f, ny = 0.f, nz = 0.f;
    if (lane < K_PTS) {
        nx = ng[lane*3 + 0]; ny = ng[lane*3 + 1]; nz = ng[lane*3 + 2];
    }
    float sx = nx, sy = ny, sz = nz;
    #pragma unroll
    for (int m = 32; m; m >>= 1) {
        sx += __shfl_xor(sx, m);
        sy += __shfl_xor(sy, m);
        sz += __shfl_xor(sz, m);
    }
    const float mg0 = sx * (1.0f/K_PTS), mg1 = sy * (1.0f/K_PTS), mg2 = sz * (1.0f/K_PTS);
    float cxx=0.f, cxy=0.f, cxz=0.f, cyy=0.f, cyz=0.f, czz=0.f;
    if (lane < K_PTS) {
        const float a = nx - mg0, b = ny - mg1, c = nz - mg2;
        cxx = a*a; cxy = a*b; cxz = a*c;
        cyy = b*b; cyz = b*c; czz = c*c;
    }
    #pragma unroll
    for (int m = 32; m; m >>= 1) {
        cxx += __shfl_xor(cxx, m); cxy += __shfl_xor(cxy, m);
        cxz += __shfl_xor(cxz, m); cyy += __shfl_xor(cyy, m);
        cyz += __shfl_xor(cyz, m); czz += __shfl_xor(czz, m);
    }
    {
        const float inv = 1.0f/(K_PTS-1);
        cxx*=inv; cxy*=inv; cxz*=inv; cyy*=inv; cyz*=inv; czz*=inv;
    }
    float cg;
    {
        const float tr = cxx + cyy + czz;
        const float q  = tr * (1.0f/3.0f);
        const float p1 = cxy*cxy + cxz*cxz + cyz*cyz;
        float eigmin;
        if (p1 < 1e-30f) {
            eigmin = fminf(fminf(cxx, cyy), czz);
        } else {
            const float a00 = cxx-q, a11 = cyy-q, a22 = czz-q;
            const float p2 = a00*a00 + a11*a11 + a22*a22 + 2.0f*p1;
            const float pp = sqrtf(p2 * (1.0f/6.0f));
            const float ip = 1.0f/pp;
            const float b00=a00*ip, b11=a11*ip, b22=a22*ip;
            const float b01=cxy*ip, b02=cxz*ip, b12=cyz*ip;
            float detB = b00*(b11*b22 - b12*b12)
                       - b01*(b01*b22 - b12*b02)
                       + b02*(b01*b12 - b11*b02);
            float r = 0.5f * detB;
            r = fminf(1.0f, fmaxf(-1.0f, r));
            const float phi = acosf(r) * (1.0f/3.0f);
            eigmin = q + 2.0f*pp*__cosf(phi + 2.0943951023931953f); // smallest root
        }
        cg = eigmin / (tr + 1e-6f);
    }

    // ---- this wave's half: per-lane point coords ----
    const int   row = h*16 + pt;                 // output row (point index)
    const float* xg = xyz + (size_t)g * (K_PTS * 3);
    const float x0 = xg[row*3 + 0], x1 = xg[row*3 + 1], x2 = xg[row*3 + 2];

    // Build F-fragments: lane holds F[row][k = ks*32 + hi*8 + j]
    bf16x8 f[5];
    #pragma unroll
    for (int ks = 0; ks < 4; ++ks) {
        #pragma unroll
        for (int j = 0; j < 8; ++j) {
            const int   k  = ks*32 + hi*8 + j;          // < 128: always RBF
            const int   d  = (k * 1525) >> 16;          // k / 43
            const float ff = (float)(k - d*43);
            const float fv = (ff + 1.0f) * (1.0f/22.0f) - 1.0f;
            const float s  = (d==0) ? x0 : ((d==1) ? x1 : x2);
            const float t  = s - fv;
            f[ks][j] = (__bf16)__expf(-2.0f*t*t);
        }
    }
    {   // ks = 4: k = 128 + hi*8 + j  -> rbf(128) | curv | lap | bias-1 | zeros
        bf16x8 a4;
        #pragma unroll
        for (int j = 0; j < 8; ++j) a4[j] = (__bf16)0.0f;
        if (hi == 0) {
            const float fv = 43.0f*(1.0f/22.0f) - 1.0f;   // k=128 -> d=2, f=42
            const float t  = x2 - fv;
            a4[0] = (__bf16)__expf(-2.0f*t*t);
            a4[1] = (__bf16)cg;
            a4[2] = (__bf16)fabsf(x0-mg0);
            a4[3] = (__bf16)fabsf(x1-mg1);
            a4[4] = (__bf16)fabsf(x2-mg2);
            a4[5] = (__bf16)1.0f;
        }
        f[4] = a4;
    }

    // ---- 12 N-tiles: MFMA and deposit into swizzled LDS ----
    #pragma unroll
    for (int nl = 0; nl < 12; ++nl) {
        const int nt = tb + nl;
        f32x4 a = {};
        #pragma unroll
        for (int ks = 0; ks < 5; ++ks) {
            const bf16x8 w = *reinterpret_cast<const bf16x8*>(
                wf + (((size_t)(ks*24 + nt)) * 64 + lane) * 8);
            a = __builtin_amdgcn_mfma_f32_16x16x32_bf16(w, f[ks], a, 0, 0, 0);
        }
        // lane's f32x4 = channels nt*16 + hi*4 + (0..3) of point `row`
        const int slot = nt*4 + hi;                         // 0..95
        const int sp   = (slot & ~15) | ((slot & 15) ^ pt); // XOR swizzle (row&15 == pt)
        lbuf[row*96 + sp] = a;
    }
    __syncthreads();

    // ---- stream the whole 48-KB group region out, perfectly contiguous ----
    float* outg = out + (size_t)g * (K_PTS * OUTD);
    const int t = threadIdx.x;
    #pragma unroll
    for (int k = 0; k < 12; ++k) {
        const int s  = k*256 + t;          // flat f32x4 index, 0..3071
        const int r  = s / 96;             // row 0..31 (magic-mul)
        const int sl = s - r*96;           // slot 0..95
        const int sp = (sl & ~15) | ((sl & 15) ^ (r & 15));
        const f32x4 v = lbuf[r*96 + sp];
        __builtin_nontemporal_store(v, reinterpret_cast<f32x4*>(outg) + s);
    }
}

extern "C" void kernel_launch(void* const* d_in, const int* in_sizes, int n_in,
                              void* d_out, int out_size, void* d_ws, size_t ws_size,
                              hipStream_t stream) {
    const float* xyz  = (const float*)d_in[0];
    const float* nxyz = (const float*)d_in[1];
    const float* W    = (const float*)d_in[2];
    const float* bias = (const float*)d_in[3];
    float* out = (float*)d_out;

    __bf16* wf = (__bf16*)d_ws;   // 61440 * 2 = 120 KB packed weight+bias

    wprep_kernel<<<(5*24*64*8 + 255)/256, 256, 0, stream>>>(W, bias, wf);
    main_kernel<<<G_TOTAL, 256, 0, stream>>>(xyz, nxyz, wf, out);
}